// Round 3
// baseline (447.393 us; speedup 1.0000x reference)
//
#include <hip/hip_runtime.h>
#include <math.h>

#define BB 8
#define CC 128
#define HH 128
#define WW 128

#define TH 8
#define TW 8
#define NCY 10
#define NCX 10
#define NCOL 100

#define K7 7
#define K19 19
#define K43 43
#define R7 3
#define R19 9
#define R43 21

#define XOFF 21          // zero padding each side of channel axis in LDS
#define CSX 171          // 21 + 128 + 21 + 1 spare -> odd stride, bank-conflict-free
#define CSV 129          // vol stride (odd)

struct Kers {
    float k7[K7];
    float k19[K19];
    float k43[K43];
};

// ---------------- tiny MLP: weights = sigmoid(relu(meta@w1^T+b1)@w2^T+b2) ----
__global__ void __launch_bounds__(192) mlp_kernel(
        const float* __restrict__ meta, const float* __restrict__ w1,
        const float* __restrict__ b1, const float* __restrict__ w2,
        const float* __restrict__ b2, float* __restrict__ wout) {
    __shared__ float hbuf[BB * 24];
    int t = threadIdx.x;
    if (t < BB * 24) {
        int b = t / 24, j = t - b * 24;
        float s = b1[j];
        #pragma unroll
        for (int i = 0; i < 12; ++i) s = fmaf(meta[b * 12 + i], w1[j * 12 + i], s);
        hbuf[t] = fmaxf(s, 0.0f);
    }
    __syncthreads();
    if (t < BB * 3) {
        int b = t / 3, o = t - b * 3;
        float s = b2[o];
        #pragma unroll
        for (int j = 0; j < 24; ++j) s = fmaf(hbuf[b * 24 + j], w2[o * 24 + j], s);
        wout[t] = 1.0f / (1.0f + expf(-s));   // only o<3 (alpha,beta,gamma) used
    }
}

// ---------------- fused gradient kernel: one block per 8x8 output tile -------
__global__ void __launch_bounds__(256, 1) holo_kernel(
        const float* __restrict__ x, const float* __restrict__ wabc,
        float* __restrict__ out, Kers kers) {
    __shared__ float xs[NCOL * CSX];    // 100 cols x (pad+128+pad), 68.4 KB
    __shared__ float vol[NCOL * CSV];   // |conv19| per col,          51.6 KB
    __shared__ float mimg[NCOL];        // band mean per col

    const int tid = threadIdx.x;
    const int b  = blockIdx.z;
    const int h0 = blockIdx.y * TH;
    const int w0 = blockIdx.x * TW;

    // ---- Phase 1: zero channel pads, then load tile+halo columns ----
    for (int idx = tid; idx < NCOL * 2 * XOFF; idx += 256) {
        int q = idx / (2 * XOFF);
        int r = idx - q * (2 * XOFF);
        int slot = (r < XOFF) ? r : (XOFF + CC + (r - XOFF));
        xs[q * CSX + slot] = 0.0f;
    }
    const float* xb = x + (size_t)b * CC * HH * WW;
    for (int idx = tid; idx < NCOL * CC; idx += 256) {
        int c = idx / NCOL;              // lanes walk q fastest -> near-coalesced
        int q = idx - c * NCOL;
        int qy = q / NCX, qx = q - qy * NCX;
        int hh = h0 - 1 + qy, ww = w0 - 1 + qx;
        float v = 0.0f;                  // zero-pad outside image (matches conv pad)
        if (hh >= 0 && hh < HH && ww >= 0 && ww < WW)
            v = xb[(size_t)c * (HH * WW) + hh * WW + ww];
        xs[q * CSX + XOFF + c] = v;
    }
    __syncthreads();

    // ---- Phase 2: vol = |conv19 along C| for all 100 columns ----
    for (int idx = tid; idx < NCOL * CC; idx += 256) {
        int c = idx / NCOL;
        int q = idx - c * NCOL;
        const float* col = &xs[q * CSX + XOFF + c - R19];
        float s = 0.0f;
        #pragma unroll
        for (int j = 0; j < K19; ++j) s = fmaf(kers.k19[j], col[j], s);
        vol[q * CSV + c] = fabsf(s);
    }
    // ---- Phase 3: band-mean per column (threads 0..99) ----
    if (tid < NCOL) {
        const float* col = &xs[tid * CSX + XOFF];
        float s = 0.0f;
        for (int c = 0; c < CC; ++c) s += col[c];
        mimg[tid] = s * (1.0f / CC);
    }
    __syncthreads();

    // ---- Phase 4: per-pixel gradients; 4 lanes share one pixel ----
    const int p   = tid >> 2;            // 0..63 : which output pixel
    const int sub = tid & 3;             // 0..3  : channel subset (interleaved)
    const int py = p >> 3, px = p & 7;
    const int q  = (py + 1) * NCX + (px + 1);
    const float* colx = &xs[q * CSX + XOFF];

    float g1 = 0.0f, g2 = 0.0f, g3 = 0.0f, macc = 0.0f;
    for (int i = 0; i < 32; ++i) {
        const int c = sub + 4 * i;
        float s7 = 0.0f;
        #pragma unroll
        for (int j = 0; j < K7; ++j) s7 = fmaf(kers.k7[j], colx[c + j - R7], s7);
        g1 += fabsf(s7);
        float s43 = 0.0f;
        #pragma unroll
        for (int j = 0; j < K43; ++j) s43 = fmaf(kers.k43[j], colx[c + j - R43], s43);
        g3 += fabsf(s43);

        const int vq = q * CSV + c;
        float v_mm = vol[vq - 11 * CSV], v_m0 = vol[vq - 10 * CSV], v_mp = vol[vq - 9 * CSV];
        float v_0m = vol[vq - 1 * CSV],                              v_0p = vol[vq + 1 * CSV];
        float v_pm = vol[vq + 9 * CSV],  v_p0 = vol[vq + 10 * CSV],  v_pp = vol[vq + 11 * CSV];
        g2 += vol[vq];
        float mx = (v_mp - v_mm) + 2.0f * (v_0p - v_0m) + (v_pp - v_pm);
        float my = (v_pm - v_mm) + 2.0f * (v_p0 - v_m0) + (v_pp - v_mp);
        macc += sqrtf(mx * mx + my * my + 1e-8f);
    }
    // reduce over the 4 channel-subsets (consecutive lanes)
    g1   += __shfl_xor(g1, 1);   g1   += __shfl_xor(g1, 2);
    g2   += __shfl_xor(g2, 1);   g2   += __shfl_xor(g2, 2);
    g3   += __shfl_xor(g3, 1);   g3   += __shfl_xor(g3, 2);
    macc += __shfl_xor(macc, 1); macc += __shfl_xor(macc, 2);

    if (sub == 0) {
        float spec = fmaxf(fmaxf(g1, g2), g3) * (1.0f / CC);
        float mix  = macc * (1.0f / CC);
        // Sobel of band-mean image
        float m_mm = mimg[q - 11], m_m0 = mimg[q - 10], m_mp = mimg[q - 9];
        float m_0m = mimg[q - 1],                        m_0p = mimg[q + 1];
        float m_pm = mimg[q + 9],  m_p0 = mimg[q + 10],  m_pp = mimg[q + 11];
        float gx = (m_mp - m_mm) + 2.0f * (m_0p - m_0m) + (m_pp - m_pm);
        float gy = (m_pm - m_mm) + 2.0f * (m_p0 - m_m0) + (m_pp - m_mp);
        float sg = sqrtf(gx * gx + gy * gy + 1e-8f);

        float al = wabc[b * 3 + 0], be = wabc[b * 3 + 1], ga = wabc[b * 3 + 2];
        float o = sqrtf(al * sg * sg + be * spec * spec + ga * mix * mix + 1e-8f);
        out[((size_t)b * HH + (h0 + py)) * WW + (w0 + px)] = o;
    }
}

// ---------------- host side --------------------------------------------------
static void make_ker(float sigma, int k, float* outk) {
    int half = k / 2;
    float asum = 0.0f;
    for (int i = 0; i < k; ++i) {
        float xx = (float)(i - half);
        float v = -xx / (sigma * sigma * sigma) * expf(-xx * xx / (2.0f * sigma * sigma));
        outk[i] = v;
        asum += fabsf(v);
    }
    for (int i = 0; i < k; ++i) outk[i] /= asum;
}

extern "C" void kernel_launch(void* const* d_in, const int* in_sizes, int n_in,
                              void* d_out, int out_size, void* d_ws, size_t ws_size,
                              hipStream_t stream) {
    const float* x    = (const float*)d_in[0];
    const float* meta = (const float*)d_in[1];
    const float* w1   = (const float*)d_in[2];
    const float* b1   = (const float*)d_in[3];
    const float* w2   = (const float*)d_in[4];
    const float* b2   = (const float*)d_in[5];
    float* outp = (float*)d_out;
    float* wabc = (float*)d_ws;          // 24 floats: per-batch alpha,beta,gamma

    Kers kers;
    make_ker(1.0f, K7,  kers.k7);
    make_ker(3.0f, K19, kers.k19);
    make_ker(7.0f, K43, kers.k43);

    mlp_kernel<<<1, 192, 0, stream>>>(meta, w1, b1, w2, b2, wabc);

    dim3 grid(WW / TW, HH / TH, BB);     // 16 x 16 x 8
    holo_kernel<<<grid, 256, 0, stream>>>(x, wabc, outp, kers);
}

// Round 8
// 188.029 us; speedup vs baseline: 2.3794x; 2.3794x over previous
//
#include <hip/hip_runtime.h>
#include <math.h>

#define BB 8
#define CC 128
#define HH 128
#define WW 128
#define HWs (HH * WW)

#define TH 8
#define TW 8
#define NCX 10
#define NCOL 100

#define K7 7
#define K19 19
#define K43 43

#define XPAD 24          // front zero-pad (channels) in xs, also back pad 24 + 8 gap
#define CSX 184          // xs column stride in ushorts = 368 B = 23 x 16B (odd groups)
#define CSV 168          // vol column stride in ushorts = 336 B = 21 x 16B (odd)
#define VSUB 40          // vol subchunk stride in ushorts = 80 B = 5 x 16B (odd)

struct Kers { float k7[K7]; float k19[K19]; float k43[K43]; };

__device__ __forceinline__ ushort f2bf(float f) {        // RNE f32 -> bf16
    uint u = __float_as_uint(f);
    u += 0x7FFFu + ((u >> 16) & 1u);
    return (ushort)(u >> 16);
}
__device__ __forceinline__ float bflo(uint u) { return __uint_as_float(u << 16); }
__device__ __forceinline__ float bfhi(uint u) { return __uint_as_float(u & 0xFFFF0000u); }

// one block = one 8x8 output tile; 256 threads; 2 blocks/CU (71 KB LDS)
__global__ void __launch_bounds__(256, 2) holo_kernel(
        const float* __restrict__ x, const float* __restrict__ meta,
        const float* __restrict__ w1, const float* __restrict__ b1,
        const float* __restrict__ w2, const float* __restrict__ b2,
        float* __restrict__ out, Kers kers) {
    __shared__ __align__(16) ushort xs[NCOL * CSX];   // 36.8 KB bf16, padded columns
    __shared__ __align__(16) ushort vol[NCOL * CSV];  // 33.6 KB bf16 |conv19|
    __shared__ float mimg[NCOL];
    __shared__ float hbuf[24];
    __shared__ float abg[3];

    const int tid = threadIdx.x;
    // bijective XCD swizzle: 2048 wgs = 8 XCD x 256; XCD k owns batch k entirely
    const int wg  = blockIdx.x;
    const int swz = (wg & 7) * 256 + (wg >> 3);
    const int b   = swz >> 8;
    const int rem = swz & 255;
    const int h0  = (rem >> 4) * TH;
    const int w0  = (rem & 15) * TW;

    // ---- MLP stage 1 (hidden layer), piggybacked on phase 1 ----
    if (tid < 24) {
        float s = b1[tid];
        #pragma unroll
        for (int i = 0; i < 12; ++i) s = fmaf(meta[b * 12 + i], w1[tid * 12 + i], s);
        hbuf[tid] = fmaxf(s, 0.0f);
    }

    // ---- Phase 1: global f32 -> bf16 LDS, unified zero-pad map ----
    // column = 184 ushorts: [0,24) zero | [24,152) 128 ch | [152,176) zero | [176,184) gap
    const float* xb = x + (size_t)b * (CC * HWs);
    for (int idx = tid; idx < NCOL * 46; idx += 256) {
        const int q  = idx % NCOL;
        const int s4 = idx / NCOL;               // 4-ushort slot 0..45
        uint lo = 0, hi = 0;
        if (s4 >= 6 && s4 < 38) {
            const int c  = 4 * s4 - XPAD;
            const int hh = h0 - 1 + q / NCX, ww = w0 - 1 + q % NCX;
            if ((unsigned)hh < HH && (unsigned)ww < WW) {
                const float* gp = xb + (size_t)c * HWs + hh * WW + ww;
                lo = (uint)f2bf(gp[0])       | ((uint)f2bf(gp[HWs])     << 16);
                hi = (uint)f2bf(gp[2 * HWs]) | ((uint)f2bf(gp[3 * HWs]) << 16);
            }
        }
        *(uint2*)(xs + q * CSX + 4 * s4) = make_uint2(lo, hi);
    }
    __syncthreads();

    // ---- MLP stage 2 (alpha,beta,gamma) ----
    if (tid < 3) {
        float s = b2[tid];
        #pragma unroll
        for (int j = 0; j < 24; ++j) s = fmaf(hbuf[j], w2[tid * 24 + j], s);
        abg[tid] = 1.0f / (1.0f + expf(-s));
    }

    // ---- Phase 2: vol = |conv19 along C|, register-window, 32-ch chunks ----
    for (int it = tid; it < NCOL * 4; it += 256) {
        const int q = it % NCOL, k = it / NCOL;  // chunk c0 = 32k
        const uint4* wp = (const uint4*)(xs + q * CSX + 8 + 32 * k); // ch c0-16 aligned
        float f2[64];
        #pragma unroll
        for (int t = 0; t < 8; ++t) {
            uint4 u = wp[t];
            f2[8*t+0]=bflo(u.x); f2[8*t+1]=bfhi(u.x); f2[8*t+2]=bflo(u.y); f2[8*t+3]=bfhi(u.y);
            f2[8*t+4]=bflo(u.z); f2[8*t+5]=bfhi(u.z); f2[8*t+6]=bflo(u.w); f2[8*t+7]=bfhi(u.w);
        }
        uint ov[16];                             // 32 bf16 channels = 16 packed uints
        #pragma unroll
        for (int m = 0; m < 32; ++m) {
            float s = 0.0f;
            #pragma unroll
            for (int j = 0; j < K19; ++j) s = fmaf(kers.k19[j], f2[m + 7 + j], s);
            const ushort hv = f2bf(fabsf(s));
            if ((m & 1) == 0) ov[m >> 1] = hv; else ov[m >> 1] |= (uint)hv << 16;
        }
        uint4* vp = (uint4*)(vol + q * CSV + VSUB * k);
        vp[0] = make_uint4(ov[0],  ov[1],  ov[2],  ov[3]);
        vp[1] = make_uint4(ov[4],  ov[5],  ov[6],  ov[7]);
        vp[2] = make_uint4(ov[8],  ov[9],  ov[10], ov[11]);
        vp[3] = make_uint4(ov[12], ov[13], ov[14], ov[15]);
    }
    // ---- Phase 3: band-mean per column (vectorized, high tids) ----
    if (tid >= 156) {
        const int col = tid - 156;
        const uint4* cp = (const uint4*)(xs + col * CSX + XPAD);
        float s = 0.0f;
        #pragma unroll
        for (int t = 0; t < 16; ++t) {
            uint4 u = cp[t];
            s += bflo(u.x) + bfhi(u.x) + bflo(u.y) + bfhi(u.y)
               + bflo(u.z) + bfhi(u.z) + bflo(u.w) + bfhi(u.w);
        }
        mimg[col] = s * (1.0f / CC);
    }
    __syncthreads();

    // ---- Phase 4: 4 lanes per pixel, contiguous 32-ch chunk each ----
    const int p = tid >> 2, sub = tid & 3;
    const int py = p >> 3, px = p & 7;
    const int q  = (py + 1) * NCX + (px + 1);

    // A) conv7 + conv43 from one 80-elem register window (channels c0-24..c0+55)
    float g1 = 0.0f, g3 = 0.0f;
    {
        float f[80];
        const uint4* ap = (const uint4*)(xs + q * CSX + 32 * sub);
        #pragma unroll
        for (int t = 0; t < 10; ++t) {
            uint4 u = ap[t];
            f[8*t+0]=bflo(u.x); f[8*t+1]=bfhi(u.x); f[8*t+2]=bflo(u.y); f[8*t+3]=bfhi(u.y);
            f[8*t+4]=bflo(u.z); f[8*t+5]=bfhi(u.z); f[8*t+6]=bflo(u.w); f[8*t+7]=bfhi(u.w);
        }
        #pragma unroll
        for (int m = 0; m < 32; ++m) {
            float s43 = 0.0f;
            #pragma unroll
            for (int j = 0; j < K43; ++j) s43 = fmaf(kers.k43[j], f[m + 3 + j], s43);
            float s7 = 0.0f;
            #pragma unroll
            for (int j = 0; j < K7; ++j) s7 = fmaf(kers.k7[j], f[m + 21 + j], s7);
            g3 += fabsf(s43);
            g1 += fabsf(s7);
        }
    }
    // B) vol center mean + mixed Sobel, 8 channels at a time
    float g2 = 0.0f, macc = 0.0f;
    const int nq[9] = { q-11, q-10, q-9, q-1, q, q+1, q+9, q+10, q+11 };
    #pragma unroll
    for (int ss = 0; ss < 4; ++ss) {
        uint4 u[9];
        #pragma unroll
        for (int n = 0; n < 9; ++n)
            u[n] = *(const uint4*)(vol + nq[n] * CSV + sub * VSUB + 8 * ss);
        #pragma unroll
        for (int t = 0; t < 8; ++t) {
            float v[9];
            #pragma unroll
            for (int n = 0; n < 9; ++n) {
                const uint w = (t & 4) ? ((t & 2) ? u[n].w : u[n].z)
                                       : ((t & 2) ? u[n].y : u[n].x);
                v[n] = (t & 1) ? bfhi(w) : bflo(w);
            }
            g2 += v[4];
            const float mx = (v[2] - v[0]) + 2.0f * (v[5] - v[3]) + (v[8] - v[6]);
            const float my = (v[6] - v[0]) + 2.0f * (v[7] - v[1]) + (v[8] - v[2]);
            macc += sqrtf(mx * mx + my * my + 1e-8f);
        }
    }
    // reduce over the 4 channel-chunks (consecutive lanes)
    g1   += __shfl_xor(g1, 1);   g1   += __shfl_xor(g1, 2);
    g2   += __shfl_xor(g2, 1);   g2   += __shfl_xor(g2, 2);
    g3   += __shfl_xor(g3, 1);   g3   += __shfl_xor(g3, 2);
    macc += __shfl_xor(macc, 1); macc += __shfl_xor(macc, 2);

    if (sub == 0) {
        const float spec = fmaxf(fmaxf(g1, g2), g3) * (1.0f / CC);
        const float mix  = macc * (1.0f / CC);
        const float m_mm = mimg[q-11], m_m0 = mimg[q-10], m_mp = mimg[q-9];
        const float m_0m = mimg[q-1],                      m_0p = mimg[q+1];
        const float m_pm = mimg[q+9],  m_p0 = mimg[q+10],  m_pp = mimg[q+11];
        const float gx = (m_mp - m_mm) + 2.0f * (m_0p - m_0m) + (m_pp - m_pm);
        const float gy = (m_pm - m_mm) + 2.0f * (m_p0 - m_m0) + (m_pp - m_mp);
        const float sg2 = gx * gx + gy * gy + 1e-8f;   // spatial_grad^2 (sqrt skipped)
        const float al = abg[0], be = abg[1], ga = abg[2];
        const float o = sqrtf(al * sg2 + be * spec * spec + ga * mix * mix + 1e-8f);
        out[((size_t)b * HH + (h0 + py)) * WW + (w0 + px)] = o;
    }
}

// ---------------- host side --------------------------------------------------
static void make_ker(float sigma, int k, float* outk) {
    int half = k / 2;
    float asum = 0.0f;
    for (int i = 0; i < k; ++i) {
        float xx = (float)(i - half);
        float v = -xx / (sigma * sigma * sigma) * expf(-xx * xx / (2.0f * sigma * sigma));
        outk[i] = v;
        asum += fabsf(v);
    }
    for (int i = 0; i < k; ++i) outk[i] /= asum;
}

extern "C" void kernel_launch(void* const* d_in, const int* in_sizes, int n_in,
                              void* d_out, int out_size, void* d_ws, size_t ws_size,
                              hipStream_t stream) {
    const float* x    = (const float*)d_in[0];
    const float* meta = (const float*)d_in[1];
    const float* w1   = (const float*)d_in[2];
    const float* b1   = (const float*)d_in[3];
    const float* w2   = (const float*)d_in[4];
    const float* b2   = (const float*)d_in[5];
    float* outp = (float*)d_out;

    Kers kers;
    make_ker(1.0f, K7,  kers.k7);
    make_ker(3.0f, K19, kers.k19);
    make_ker(7.0f, K43, kers.k43);

    holo_kernel<<<BB * 16 * 16, 256, 0, stream>>>(x, meta, w1, b1, w2, b2, outp, kers);
}